// Round 4
// baseline (3983.857 us; speedup 1.0000x reference)
//
#include <hip/hip_runtime.h>
#include <hip/hip_bf16.h>
#include <math.h>

typedef __bf16 bf16_t;
typedef __bf16 bf16x8 __attribute__((ext_vector_type(8)));
typedef float  f32x4  __attribute__((ext_vector_type(4)));

// ---------------- workspace layout (bytes) ----------------
#define WS_WSP    0        // 1297 f32  : collapsed spatial weight vector
#define WS_AH     5248     // 256 f32   : head weights applied to h_T
#define WS_U527   6272     // 527 f32   : intermediate for seg composition
#define WS_BIAS   8384     // 1 f32     : total scalar bias
#define WS_BIASG  8448     // 1024 f32  : gate bias (b_ih + b_hh)
#define WS_WC     12544    // 327680 bf16 (655360 B): fragment-swizzled [x|h] weights

__device__ __forceinline__ float sigmoidf_fast(float x) {
    return 1.f / (1.f + __expf(-x));
}
__device__ __forceinline__ float tanhf_fast(float x) {
    float ax = fabsf(x);
    float t  = __expf(-2.f * ax);
    float r  = (1.f - t) / (1.f + t);
    return copysignf(r, x);
}

// ---------------- head/spatial weight composition (tiny) ----------------
__global__ void k_head(const float* __restrict__ sl_w, const float* __restrict__ sl_b,
                       const float* __restrict__ st_w, const float* __restrict__ st_b,
                       const float* __restrict__ seg_b,
                       const float* __restrict__ l1_w, const float* __restrict__ l1_b,
                       const float* __restrict__ l2_w, const float* __restrict__ l2_b,
                       const float* __restrict__ l4_w, const float* __restrict__ l4_b,
                       const float* __restrict__ l5_w, const float* __restrict__ l5_b,
                       const float* __restrict__ l6_w, const float* __restrict__ l6_b,
                       const float* __restrict__ l7_w, const float* __restrict__ l7_b,
                       float* __restrict__ wsp, float* __restrict__ ah,
                       float* __restrict__ u527_out, float* __restrict__ bias_out) {
    __shared__ float v2[128], v3[256], aa[384], u256[256], u527[527];
    __shared__ float red[8];
    const int t = threadIdx.x;   // 512 threads

    if (t < 128) { float s = 0.f; for (int i = 0; i < 128; ++i) s += l7_w[i] * l6_w[i*128 + t]; v2[t] = s; }
    __syncthreads();
    if (t < 256) { float s = 0.f; for (int i = 0; i < 128; ++i) s += v2[i] * l5_w[i*256 + t]; v3[t] = s; }
    __syncthreads();
    if (t < 384) { float s = 0.f; for (int i = 0; i < 256; ++i) s += v3[i] * l4_w[i*384 + t]; aa[t] = s; }
    __syncthreads();
    if (t < 256) { float s = 0.f; for (int i = 0; i < 128; ++i) s += aa[i] * l2_w[i*256 + t]; u256[t] = s; }
    if (t < 256) ah[t] = aa[128 + t];
    __syncthreads();
    for (int j = t; j < 527; j += 512) {
        float s = 0.f;
        for (int i = 0; i < 256; ++i) s += u256[i] * l1_w[i*527 + j];
        u527[j] = s; u527_out[j] = s;
    }
    __syncthreads();
    if (t < 4)              { float s = 0.f; for (int i = 0; i < 2; ++i) s += u527[i]     * sl_w[i*4  + t];      wsp[t] = s; }
    else if (t < 16)        { int c = t - 4;  float s = 0.f; for (int i = 0; i < 8; ++i) s += u527[2+i] * st_w[i*12 + c]; wsp[t] = s; }
    else if (t < 21)        { wsp[1292 + (t - 16)] = u527[522 + (t - 16)]; }
    float p = 0.f;
    if (t < 128) p += l7_w[t] * l6_b[t] + v2[t] * l5_b[t] + aa[t] * l2_b[t];
    if (t < 256) p += v3[t] * l4_b[t] + u256[t] * l1_b[t];
    if (t < 2)   p += u527[t] * sl_b[t];
    if (t < 8)   p += u527[2 + t] * st_b[t];
    p += u527[10 + t] * seg_b[t];
    p += __shfl_xor(p, 1);  p += __shfl_xor(p, 2);  p += __shfl_xor(p, 4);
    p += __shfl_xor(p, 8);  p += __shfl_xor(p, 16); p += __shfl_xor(p, 32);
    if ((t & 63) == 0) red[t >> 6] = p;
    __syncthreads();
    if (t == 0) {
        float s = l7_b[0];
        for (int i = 0; i < 8; ++i) s += red[i];
        *bias_out = s;
    }
}

__global__ void k_seg(const float* __restrict__ seg_w, const float* __restrict__ u527,
                      float* __restrict__ wsp) {
    int j = blockIdx.x * 256 + threadIdx.x;
    if (j >= 1276) return;
    float s = 0.f;
    for (int i = 0; i < 512; ++i) s += u527[10 + i] * seg_w[i*1276 + j];
    wsp[16 + j] = s;
}

// Build fragment-swizzled bf16 combined weights Wc and gate bias.
// Logical W: [n=1024][k=320], k<56: w_ih, 56<=k<64: 0 (pad), k>=64: w_hh[k-64].
// Physical: elem for (ntile=n>>4, kk=k>>5) at ((ntile*10+kk)*64 + lane)*8 + e
// with n = ntile*16 + (lane&15), k = kk*32 + (lane>>4)*8 + e.
__global__ void k_wc(const float* __restrict__ w_ih, const float* __restrict__ b_ih,
                     const float* __restrict__ w_hh, const float* __restrict__ b_hh,
                     bf16_t* __restrict__ wc, float* __restrict__ biasg) {
    int idx = blockIdx.x * 256 + threadIdx.x;
    if (idx < 1024) biasg[idx] = b_ih[idx] + b_hh[idx];
    if (idx < 1024 * 320) {
        int e  = idx & 7;
        int l  = (idx >> 3) & 63;
        int t2 = idx >> 9;
        int kk = t2 % 10;
        int nt = t2 / 10;
        int n  = nt * 16 + (l & 15);
        int k  = kk * 32 + ((l >> 4) << 3) + e;
        float v = 0.f;
        if (k < 56)       v = w_ih[n*56 + k];
        else if (k >= 64) v = w_hh[n*256 + (k - 64)];
        wc[idx] = (bf16_t)v;
    }
}

// out[b] = dot(spatial[b], w_sp) + bias   (one wave per row)
__global__ void k_spatial(const float* __restrict__ sp, const float* __restrict__ wsp,
                          const float* __restrict__ bias, float* __restrict__ out) {
    int row  = blockIdx.x * 4 + (threadIdx.x >> 6);
    int lane = threadIdx.x & 63;
    const float* rp = sp + (size_t)row * 1297;
    float s = 0.f;
    for (int k = lane; k < 1297; k += 64) s += rp[k] * wsp[k];
    s += __shfl_xor(s, 1);  s += __shfl_xor(s, 2);  s += __shfl_xor(s, 4);
    s += __shfl_xor(s, 8);  s += __shfl_xor(s, 16); s += __shfl_xor(s, 32);
    if (lane == 0) out[row] = s + bias[0];
}

// ---------------- LSTM: pipelined weight stream, 256 blocks x 64 rows, 8 waves ----------------
// At (LDS): [64 rows][328 bf16]: cols 0..55 = x_t, 56..63 = 0, 64..319 = h.
// Xf (LDS): [64][56] f32: x_{t+1} staged via global_load_lds during phase A.
// Wave w owns hidden dims [32w,32w+32); two gate-pair passes: (i,g) then (f,o).
// Weight chunks stream through 4 rotating reg buffers, issued 4 chunks ahead;
// tail issues stay in flight across phase B (never drained to vmcnt 0).
__launch_bounds__(512, 2)
__global__ void k_lstm(const float* __restrict__ temporal, const bf16_t* __restrict__ wc,
                       const float* __restrict__ biasg, const float* __restrict__ ah,
                       float* __restrict__ out) {
    __shared__ bf16_t At[64 * 328];
    __shared__ float  Xf[64 * 56];
    const int tid  = threadIdx.x;
    const int lane = tid & 63;
    const int w    = tid >> 6;          // wave 0..7
    const int row0 = blockIdx.x * 64;
    const int l15  = lane & 15;
    const int l4q  = lane >> 4;         // 0..3

    // weight fragment offsets (elements): pass p, frag f -> gate q=2*(f>>1)+p, u=f&1
    int woff[2][4];
#pragma unroll
    for (int p = 0; p < 2; ++p)
#pragma unroll
        for (int f = 0; f < 4; ++f) {
            int ntg = (2*(f>>1) + p)*16 + 2*w + (f&1);
            woff[p][f] = ntg*10*512 + lane*8;
        }

    float bias[2][4];
#pragma unroll
    for (int p = 0; p < 2; ++p)
#pragma unroll
        for (int f = 0; f < 4; ++f)
            bias[p][f] = biasg[(2*(f>>1)+p)*256 + 32*w + 16*(f&1) + l15];

    bf16x8 W[4][4];                     // [buf][frag]
    auto wissue = [&](int buf, int chunk) {   // chunk in [0,20)
        int pp = chunk / 10, kk = chunk % 10;
#pragma unroll
        for (int f = 0; f < 4; ++f)
            W[buf][f] = *reinterpret_cast<const bf16x8*>(wc + woff[pp][f] + kk*512);
    };

    // x staging: wave w loads rows 8w..8w+7, lanes 0..13 x 16B each
    auto xissue = [&](int t) {
        if (lane < 14) {
#pragma unroll
            for (int rr = 0; rr < 8; ++rr) {
                int r = w*8 + rr;
                const float* g = temporal + (size_t)(row0 + r)*5376 + (size_t)t*56 + lane*4;
                __builtin_amdgcn_global_load_lds(
                    (const __attribute__((address_space(1))) uint32_t*)g,
                    (__attribute__((address_space(3))) uint32_t*)&Xf[r*56], 16, 0, 0);
            }
        }
    };

    f32x4 cst[4][2];
#pragma unroll
    for (int rt = 0; rt < 4; ++rt)
#pragma unroll
        for (int u = 0; u < 2; ++u) cst[rt][u] = (f32x4){0.f, 0.f, 0.f, 0.f};

    // ---- prologue: stage x_0, zero h/pad region, preload weight chunks 0..3 ----
    xissue(0);
    wissue(0, 0); wissue(1, 1); wissue(2, 2); wissue(3, 3);
    for (int i = tid; i < 64*272; i += 512) {
        int r = i / 272, cc = i - r*272;
        At[r*328 + 56 + cc] = (bf16_t)0.f;
    }
    asm volatile("s_waitcnt vmcnt(16)" ::: "memory");   // x done (weights may stay in flight)
    {
        int r = tid >> 3, sub = tid & 7;
#pragma unroll
        for (int e = 0; e < 7; ++e)
            At[r*328 + sub*7 + e] = (bf16_t)Xf[r*56 + sub*7 + e];
    }
    __syncthreads();

    const int hcolb = 64 + 32*w;

#pragma unroll 1
    for (int t = 0; t < 96; ++t) {
        if (t < 95) xissue(t + 1);

        f32x4 acc[4][4];
        f32x4 P[4][2];

        // ---- pass 1: gates (i,g), chunks 0..9 ----
#pragma unroll
        for (int rt = 0; rt < 4; ++rt)
#pragma unroll
            for (int f = 0; f < 4; ++f)
                acc[rt][f] = (f32x4){bias[0][f], bias[0][f], bias[0][f], bias[0][f]};
#pragma unroll
        for (int c = 0; c < 10; ++c) {
            bf16x8 af[4];
#pragma unroll
            for (int rt = 0; rt < 4; ++rt)
                af[rt] = *reinterpret_cast<const bf16x8*>(&At[(16*rt + l15)*328 + l4q*8 + c*32]);
#pragma unroll
            for (int f = 0; f < 4; ++f)
#pragma unroll
                for (int rt = 0; rt < 4; ++rt)
                    acc[rt][f] = __builtin_amdgcn_mfma_f32_16x16x32_bf16(
                        af[rt], W[c & 3][f], acc[rt][f], 0, 0, 0);
            wissue(c & 3, c + 4);           // chunks 4..13
        }

        // ---- P = sigmoid(i) * tanh(g) (overlaps other wave's MFMAs) ----
#pragma unroll
        for (int rt = 0; rt < 4; ++rt)
#pragma unroll
            for (int u = 0; u < 2; ++u)
#pragma unroll
                for (int e = 0; e < 4; ++e)
                    P[rt][u][e] = sigmoidf_fast(acc[rt][u][e]) * tanhf_fast(acc[rt][2+u][e]);

        // ---- pass 2: gates (f,o), chunks 10..19 ----
#pragma unroll
        for (int rt = 0; rt < 4; ++rt)
#pragma unroll
            for (int f = 0; f < 4; ++f)
                acc[rt][f] = (f32x4){bias[1][f], bias[1][f], bias[1][f], bias[1][f]};
#pragma unroll
        for (int c = 10; c < 20; ++c) {
            bf16x8 af[4];
            int kk = c - 10;
#pragma unroll
            for (int rt = 0; rt < 4; ++rt)
                af[rt] = *reinterpret_cast<const bf16x8*>(&At[(16*rt + l15)*328 + l4q*8 + kk*32]);
#pragma unroll
            for (int f = 0; f < 4; ++f)
#pragma unroll
                for (int rt = 0; rt < 4; ++rt)
                    acc[rt][f] = __builtin_amdgcn_mfma_f32_16x16x32_bf16(
                        af[rt], W[c & 3][f], acc[rt][f], 0, 0, 0);
            wissue(c & 3, (c + 4) % 20);    // chunks 14..19, then 0..3 of next step
        }

        __syncthreads();   // all At reads done before h / x writes

        // ---- phase B: c,h update; h -> At ----
#pragma unroll
        for (int rt = 0; rt < 4; ++rt)
#pragma unroll
            for (int u = 0; u < 2; ++u)
#pragma unroll
                for (int e = 0; e < 4; ++e) {
                    float fg = sigmoidf_fast(acc[rt][u][e]);
                    float og = sigmoidf_fast(acc[rt][2+u][e]);
                    float cn = fg * cst[rt][u][e] + P[rt][u][e];
                    cst[rt][u][e] = cn;
                    At[(16*rt + l4q*4 + e)*328 + hcolb + 16*u + l15] =
                        (bf16_t)(og * tanhf_fast(cn));
                }

        // ---- x_{t+1}: Xf -> At (behind counted vmcnt; 16 = in-flight weight loads) ----
        if (t < 95) {
            asm volatile("s_waitcnt vmcnt(16)" ::: "memory");
            int r = tid >> 3, sub = tid & 7;
#pragma unroll
            for (int e = 0; e < 7; ++e)
                At[r*328 + sub*7 + e] = (bf16_t)Xf[r*56 + sub*7 + e];
        }
        __syncthreads();   // writes visible before next step's reads
    }

    // ---- epilogue: out[row] += ah . h_T[row] ----
    {
        int r = tid >> 3, part = tid & 7;
        float s = 0.f;
#pragma unroll
        for (int j = 0; j < 32; ++j)
            s += ah[part*32 + j] * (float)At[r*328 + 64 + part*32 + j];
        s += __shfl_xor(s, 1); s += __shfl_xor(s, 2); s += __shfl_xor(s, 4);
        if (part == 0) out[row0 + r] += s;
    }
}

// ---------------- launch ----------------
extern "C" void kernel_launch(void* const* d_in, const int* in_sizes, int n_in,
                              void* d_out, int out_size, void* d_ws, size_t ws_size,
                              hipStream_t stream) {
    const float* spatial  = (const float*)d_in[0];
    const float* temporal = (const float*)d_in[1];
    const float* sl_w = (const float*)d_in[2];  const float* sl_b = (const float*)d_in[3];
    const float* st_w = (const float*)d_in[4];  const float* st_b = (const float*)d_in[5];
    const float* seg_w = (const float*)d_in[6]; const float* seg_b = (const float*)d_in[7];
    const float* l1_w = (const float*)d_in[8];  const float* l1_b = (const float*)d_in[9];
    const float* l2_w = (const float*)d_in[10]; const float* l2_b = (const float*)d_in[11];
    const float* w_ih = (const float*)d_in[12]; const float* b_ih = (const float*)d_in[13];
    const float* w_hh = (const float*)d_in[14]; const float* b_hh = (const float*)d_in[15];
    const float* l4_w = (const float*)d_in[16]; const float* l4_b = (const float*)d_in[17];
    const float* l5_w = (const float*)d_in[18]; const float* l5_b = (const float*)d_in[19];
    const float* l6_w = (const float*)d_in[20]; const float* l6_b = (const float*)d_in[21];
    const float* l7_w = (const float*)d_in[22]; const float* l7_b = (const float*)d_in[23];

    char* ws = (char*)d_ws;
    float*  wsp   = (float*)(ws + WS_WSP);
    float*  ah    = (float*)(ws + WS_AH);
    float*  u527  = (float*)(ws + WS_U527);
    float*  biasT = (float*)(ws + WS_BIAS);
    float*  biasg = (float*)(ws + WS_BIASG);
    bf16_t* wc    = (bf16_t*)(ws + WS_WC);

    float* out = (float*)d_out;

    hipLaunchKernelGGL(k_head, dim3(1), dim3(512), 0, stream,
                       sl_w, sl_b, st_w, st_b, seg_b, l1_w, l1_b, l2_w, l2_b,
                       l4_w, l4_b, l5_w, l5_b, l6_w, l6_b, l7_w, l7_b,
                       wsp, ah, u527, biasT);
    hipLaunchKernelGGL(k_seg, dim3(5), dim3(256), 0, stream, seg_w, u527, wsp);
    hipLaunchKernelGGL(k_wc, dim3((1024*320 + 255)/256), dim3(256), 0, stream,
                       w_ih, b_ih, w_hh, b_hh, wc, biasg);
    hipLaunchKernelGGL(k_spatial, dim3(16384/4), dim3(256), 0, stream,
                       spatial, wsp, biasT, out);
    hipLaunchKernelGGL(k_lstm, dim3(256), dim3(512), 0, stream,
                       temporal, wc, biasg, ah, out);
}